// Round 6
// baseline (4280.350 us; speedup 1.0000x reference)
//
#include <hip/hip_runtime.h>
#include <hip/hip_bf16.h>

#define B_SZ 4
#define L_SZ 512
#define D_MODEL 256
#define D_INNER 512
#define D_STATE 16
#define DT_RANK 16
#define N_LAYERS 6
#define BL (B_SZ * L_SZ)   // 2048 token rows
#define NBLK 512           // persistent grid: 512 blocks x 256 thr, 2/CU by LDS

typedef __bf16 bf16_t;
typedef __bf16 bf16x8 __attribute__((ext_vector_type(8)));
typedef __bf16 bf16x4 __attribute__((ext_vector_type(4)));
typedef float  f32x4  __attribute__((ext_vector_type(4)));

// LDS union across phases. Max member (conv) = 69232 B -> exactly 2 blocks/CU
// (138.5 KB of 160 KB), which guarantees all 512 blocks co-resident.
union SMem {
    struct { bf16_t As[64][264]; bf16_t Bs[64][72]; } win;
    struct { float xs[19][516]; bf16_t us[16][520]; f32x4 part[4][3][64]; float dtt[16][17]; } conv;
    struct { bf16_t As[16][72]; bf16_t Bs[256][72]; float rsum[16][5]; } wout;
    struct { float Ap[4][64]; float he[4][64]; } scan;
};

// All-reduce over the 16-lane DPP row via rotate-add.
__device__ __forceinline__ float row_allreduce16(float x)
{
    int v;
    v = __builtin_amdgcn_mov_dpp(__float_as_int(x), 0x121, 0xf, 0xf, true);
    x += __int_as_float(v);
    v = __builtin_amdgcn_mov_dpp(__float_as_int(x), 0x122, 0xf, 0xf, true);
    x += __int_as_float(v);
    v = __builtin_amdgcn_mov_dpp(__float_as_int(x), 0x124, 0xf, 0xf, true);
    x += __int_as_float(v);
    v = __builtin_amdgcn_mov_dpp(__float_as_int(x), 0x128, 0xf, 0xf, true);
    x += __int_as_float(v);
    return x;
}

// Grid barrier: sense-reversal via (counter, generation), leader thread only.
// Same structure as ROCm cooperative-groups grid sync: __syncthreads drains
// each wave's writes to L2; leader's __threadfence (agent scope) does the
// cross-XCD writeback/invalidate; atomics carry acquire/release ordering.
__device__ __forceinline__ void gbar(int* bar)
{
    __syncthreads();
    if (threadIdx.x == 0) {
        __threadfence();
        int* cnt = bar;
        int* gen = bar + 1;
        int g = __hip_atomic_load(gen, __ATOMIC_RELAXED, __HIP_MEMORY_SCOPE_AGENT);
        if (__hip_atomic_fetch_add(cnt, 1, __ATOMIC_ACQ_REL, __HIP_MEMORY_SCOPE_AGENT)
            == NBLK - 1) {
            __hip_atomic_store(cnt, 0, __ATOMIC_RELAXED, __HIP_MEMORY_SCOPE_AGENT);
            __hip_atomic_store(gen, g + 1, __ATOMIC_RELEASE, __HIP_MEMORY_SCOPE_AGENT);
        } else {
            while (__hip_atomic_load(gen, __ATOMIC_ACQUIRE, __HIP_MEMORY_SCOPE_AGENT) == g)
                __builtin_amdgcn_s_sleep(2);
        }
        __threadfence();
    }
    __syncthreads();
}

// ---------------------------------------------------------------------------
// P1: W_in GEMM (K=256), full-K A staging + ZSPLIT epilogue. 512 tiles = NBLK.
// ---------------------------------------------------------------------------
__device__ __forceinline__ void phase_win(
    SMem& sm, const bf16_t* __restrict__ A, const bf16_t* __restrict__ Bw,
    const float* __restrict__ bias, float* __restrict__ C, float* __restrict__ Z,
    int blk)
{
    constexpr int K = 256, BK = 64;
    const int tid  = threadIdx.x;
    const int wave = tid >> 6, lane = tid & 63;
    const int wm = wave >> 1, wn = wave & 1;
    const int lm = lane & 15, quad = lane >> 4;
    const int m0 = (blk >> 4) * 64, n0 = (blk & 15) * 64;

    #pragma unroll
    for (int i = tid; i < 64 * (K / 8); i += 256) {
        int r = i >> 5, c8 = i & 31;
        *(bf16x8*)&sm.win.As[r][c8 * 8] =
            *(const bf16x8*)(A + (size_t)(m0 + r) * K + c8 * 8);
    }

    f32x4 acc[2][2] = {};
    for (int k0 = 0; k0 < K; k0 += BK) {
        #pragma unroll
        for (int i = tid; i < 64 * (BK / 8); i += 256) {
            int r = i >> 3, c8 = i & 7;
            *(bf16x8*)&sm.win.Bs[r][c8 * 8] =
                *(const bf16x8*)(Bw + (size_t)(n0 + r) * K + k0 + c8 * 8);
        }
        __syncthreads();   // first barrier also covers the As staging
        #pragma unroll
        for (int ks = 0; ks < 2; ++ks) {
            bf16x8 af[2], bfr[2];
            #pragma unroll
            for (int i = 0; i < 2; ++i)
                af[i] = *(const bf16x8*)&sm.win.As[wm * 32 + i * 16 + lm][k0 + ks * 32 + quad * 8];
            #pragma unroll
            for (int j = 0; j < 2; ++j)
                bfr[j] = *(const bf16x8*)&sm.win.Bs[wn * 32 + j * 16 + lm][ks * 32 + quad * 8];
            #pragma unroll
            for (int i = 0; i < 2; ++i)
                #pragma unroll
                for (int j = 0; j < 2; ++j)
                    acc[i][j] = __builtin_amdgcn_mfma_f32_16x16x32_bf16(
                        af[i], bfr[j], acc[i][j], 0, 0, 0);
        }
        __syncthreads();
    }

    if (n0 >= D_INNER) {
        #pragma unroll
        for (int i = 0; i < 2; ++i) {
            int rowbase = m0 + wm * 32 + i * 16 + quad * 4;
            #pragma unroll
            for (int j = 0; j < 2; ++j) {
                int col = n0 + wn * 32 + j * 16 + lm;
                float4 o;
                #pragma unroll
                for (int r = 0; r < 4; ++r) {
                    float v = acc[i][j][r] + bias[col];
                    ((float*)&o)[r] = v / (1.f + __expf(-v));
                }
                *(float4*)(Z + (size_t)(col - D_INNER) * BL + rowbase) = o;
            }
        }
        return;
    }

    #pragma unroll
    for (int i = 0; i < 2; ++i) {
        #pragma unroll
        for (int j = 0; j < 2; ++j) {
            int col = n0 + wn * 32 + j * 16 + lm;
            #pragma unroll
            for (int r = 0; r < 4; ++r) {
                int rowm = m0 + wm * 32 + i * 16 + quad * 4 + r;
                C[(size_t)rowm * D_INNER + col] = acc[i][j][r] + bias[col];
            }
        }
    }
}

// ---------------------------------------------------------------------------
// P2: conv+silu + W_x GEMM + delta precompute. 128 tiles (blocks 0-127).
// ---------------------------------------------------------------------------
__device__ __forceinline__ void phase_conv(
    SMem& sm, const float* __restrict__ xzx, const float* __restrict__ cw,
    const bf16_t* __restrict__ Bw, const float* __restrict__ dt_w,
    const float* __restrict__ dt_b, float* __restrict__ uT,
    float* __restrict__ xdbcT, float* __restrict__ deltaT, int blk)
{
    constexpr int K = 512;
    const int tid  = threadIdx.x;
    const int wave = tid >> 6, lane = tid & 63;
    const int lm = lane & 15, quad = lane >> 4;
    const int m0 = blk * 16;

    for (int q = tid; q < 19 * 128; q += 256) {
        int rx = q >> 7, c4 = (q & 127) * 4;
        int mr = m0 - 3 + rx;
        float4 v = make_float4(0.f, 0.f, 0.f, 0.f);
        if (mr >= 0) v = *(const float4*)(xzx + (size_t)mr * K + c4);
        *(float4*)&sm.conv.xs[rx][c4] = v;
    }
    __syncthreads();

    #pragma unroll
    for (int it = 0; it < 8; ++it) {
        int item = tid + it * 256;
        int d = item >> 2, rg = item & 3;
        const float4 wv = *(const float4*)(cw + d * 4);
        float4 o;
        #pragma unroll
        for (int e = 0; e < 4; ++e) {
            int ro = rg * 4 + e;
            int t  = (m0 + ro) & (L_SZ - 1);
            float a = wv.w * sm.conv.xs[ro + 3][d];
            if (t >= 1) a += wv.z * sm.conv.xs[ro + 2][d];
            if (t >= 2) a += wv.y * sm.conv.xs[ro + 1][d];
            if (t >= 3) a += wv.x * sm.conv.xs[ro + 0][d];
            a = a / (1.f + __expf(-a));
            ((float*)&o)[e] = a;
            sm.conv.us[ro][d] = (bf16_t)a;
        }
        *(float4*)(uT + (size_t)d * BL + m0 + rg * 4) = o;
    }
    __syncthreads();

    f32x4 acc[3] = {};
    const int kb = wave * 128 + quad * 8;
    #pragma unroll
    for (int ks = 0; ks < 4; ++ks) {
        int k0 = kb + ks * 32;
        bf16x8 af = *(const bf16x8*)&sm.conv.us[lm][k0];
        #pragma unroll
        for (int j = 0; j < 3; ++j) {
            bf16x8 bfr = *(const bf16x8*)(Bw + (size_t)(j * 16 + lm) * K + k0);
            acc[j] = __builtin_amdgcn_mfma_f32_16x16x32_bf16(af, bfr, acc[j], 0, 0, 0);
        }
    }
    #pragma unroll
    for (int j = 0; j < 3; ++j) sm.conv.part[wave][j][lane] = acc[j];
    __syncthreads();

    if (tid < 192) {
        int j = tid >> 6, l = tid & 63;
        f32x4 s = sm.conv.part[0][j][l];
        s += sm.conv.part[1][j][l];
        s += sm.conv.part[2][j][l];
        s += sm.conv.part[3][j][l];
        int col = j * 16 + (l & 15);
        float4 v = make_float4(s[0], s[1], s[2], s[3]);
        *(float4*)(xdbcT + (size_t)col * BL + m0 + (l >> 4) * 4) = v;
        if (j == 0) {
            #pragma unroll
            for (int e = 0; e < 4; ++e)
                sm.conv.dtt[(l >> 4) * 4 + e][l & 15] = s[e];
        }
    }
    __syncthreads();

    #pragma unroll
    for (int it = 0; it < 8; ++it) {
        int item = tid + it * 256;
        int d = item >> 2, tg = item & 3;
        const float4 w0 = *(const float4*)(dt_w + (size_t)d * 16 + 0);
        const float4 w1 = *(const float4*)(dt_w + (size_t)d * 16 + 4);
        const float4 w2 = *(const float4*)(dt_w + (size_t)d * 16 + 8);
        const float4 w3 = *(const float4*)(dt_w + (size_t)d * 16 + 12);
        const float bdt = dt_b[d];
        float4 o;
        #pragma unroll
        for (int e = 0; e < 4; ++e) {
            int t = tg * 4 + e;
            float a = bdt;
            a += sm.conv.dtt[t][0]  * w0.x + sm.conv.dtt[t][1]  * w0.y
               + sm.conv.dtt[t][2]  * w0.z + sm.conv.dtt[t][3]  * w0.w;
            a += sm.conv.dtt[t][4]  * w1.x + sm.conv.dtt[t][5]  * w1.y
               + sm.conv.dtt[t][6]  * w1.z + sm.conv.dtt[t][7]  * w1.w;
            a += sm.conv.dtt[t][8]  * w2.x + sm.conv.dtt[t][9]  * w2.y
               + sm.conv.dtt[t][10] * w2.z + sm.conv.dtt[t][11] * w2.w;
            a += sm.conv.dtt[t][12] * w3.x + sm.conv.dtt[t][13] * w3.y
               + sm.conv.dtt[t][14] * w3.z + sm.conv.dtt[t][15] * w3.w;
            ((float*)&o)[e] = (a > 20.f) ? a : __logf(1.f + __expf(a));
        }
        *(float4*)(deltaT + (size_t)d * BL + m0 + tg * 4) = o;
    }
}

// ---------------------------------------------------------------------------
// P3: selective scan (v9 math; NW=4 waves, TC=128 tokens/wave). 512 units.
// ---------------------------------------------------------------------------
__device__ __forceinline__ void phase_scan(
    SMem& sm, const float* __restrict__ xdbcT, const float* __restrict__ deltaT,
    const float* __restrict__ uT, const float* __restrict__ szT,
    const float* __restrict__ A_log, const float* __restrict__ Dv,
    bf16_t* __restrict__ y, int blk)
{
    constexpr int TC = 128;
    const int b    = blk >> 7;
    const int dg   = blk & 127;
    const int wave = threadIdx.x >> 6, lane = threadIdx.x & 63;
    const int d    = dg * 4 + (lane >> 4);
    const int n    = lane & 15;

    const float Adn = -__expf(A_log[d * D_STATE + n]);
    const int r0 = b * L_SZ + wave * TC;

    const float* Brow = xdbcT  + (size_t)(DT_RANK + n) * BL;
    const float* Crow = xdbcT  + (size_t)(DT_RANK + D_STATE + n) * BL;
    const float* drow = deltaT + (size_t)d * BL;
    const float* urow = uT     + (size_t)d * BL;
    const float* zrow = szT    + (size_t)d * BL;

    // pass 1: chunk-end state only
    float h = 0.f, P = 1.f;
    #pragma unroll 8
    for (int j4 = 0; j4 < TC / 4; ++j4) {
        int rb = r0 + j4 * 4;
        f32x4 dl = *(const f32x4*)(drow + rb);
        f32x4 Bv = *(const f32x4*)(Brow + rb);
        f32x4 uv = *(const f32x4*)(urow + rb);
        #pragma unroll
        for (int k = 0; k < 4; ++k) {
            float dA = __expf(dl[k] * Adn);
            h = dA * h + dl[k] * uv[k] * Bv[k];
            P *= dA;
        }
    }
    sm.scan.Ap[wave][lane] = P;
    sm.scan.he[wave][lane] = h;
    __syncthreads();

    float H = 0.f;
    for (int j = 0; j < wave; ++j)
        H = sm.scan.Ap[j][lane] * H + sm.scan.he[j][lane];

    // pass 2: re-run recurrence seeded with H; emit y
    const float Dd = Dv[d];
    h = H;
    for (int g = 0; g < TC / 16; ++g) {
        float py[16];
        #pragma unroll
        for (int j4 = 0; j4 < 4; ++j4) {
            int rb = r0 + g * 16 + j4 * 4;
            f32x4 dl = *(const f32x4*)(drow + rb);
            f32x4 Bv = *(const f32x4*)(Brow + rb);
            f32x4 uv = *(const f32x4*)(urow + rb);
            f32x4 Cc = *(const f32x4*)(Crow + rb);
            #pragma unroll
            for (int k = 0; k < 4; ++k) {
                float dA = __expf(dl[k] * Adn);
                h = dA * h + dl[k] * uv[k] * Bv[k];
                py[j4 * 4 + k] = h * Cc[k];
            }
        }
        #pragma unroll
        for (int j = 0; j < 16; ++j)
            py[j] = row_allreduce16(py[j]);
        if (n == 0) {
            #pragma unroll
            for (int j4 = 0; j4 < 4; ++j4) {
                int rb = r0 + g * 16 + j4 * 4;
                f32x4 uv = *(const f32x4*)(urow + rb);
                f32x4 sz = *(const f32x4*)(zrow + rb);
                #pragma unroll
                for (int k = 0; k < 4; ++k) {
                    int row = rb + k;
                    y[(size_t)row * D_INNER + d] =
                        (bf16_t)((py[j4 * 4 + k] + uv[k] * Dd) * sz[k]);
                }
            }
        }
    }
}

// ---------------------------------------------------------------------------
// P4: W_out GEMM + residual + fused next-layer RMSNorm. 128 tiles (blk<128).
// ---------------------------------------------------------------------------
__device__ __forceinline__ void phase_wout(
    SMem& sm, const bf16_t* __restrict__ A, const bf16_t* __restrict__ Bw,
    const float* __restrict__ bias, const float* __restrict__ R,
    const float* __restrict__ nw, float* __restrict__ C,
    bf16_t* __restrict__ Xn, int blk)
{
    constexpr int K = 512, BK = 64, BM = 16, BN = 256;
    const int tid  = threadIdx.x;
    const int wave = tid >> 6, lane = tid & 63;
    const int lm = lane & 15, quad = lane >> 4;
    const int m0 = blk * BM;

    f32x4 acc[4] = {};
    for (int k0 = 0; k0 < K; k0 += BK) {
        if (tid < BM * (BK / 8)) {
            int r = tid >> 3, c8 = tid & 7;
            *(bf16x8*)&sm.wout.As[r][c8 * 8] =
                *(const bf16x8*)(A + (size_t)(m0 + r) * K + k0 + c8 * 8);
        }
        #pragma unroll
        for (int i = tid; i < BN * (BK / 8); i += 256) {
            int r = i >> 3, c8 = i & 7;
            *(bf16x8*)&sm.wout.Bs[r][c8 * 8] =
                *(const bf16x8*)(Bw + (size_t)r * K + k0 + c8 * 8);
        }
        __syncthreads();
        #pragma unroll
        for (int ks = 0; ks < 2; ++ks) {
            bf16x8 af = *(const bf16x8*)&sm.wout.As[lm][ks * 32 + quad * 8];
            #pragma unroll
            for (int j = 0; j < 4; ++j) {
                bf16x8 bfr = *(const bf16x8*)&sm.wout.Bs[wave * 64 + j * 16 + lm][ks * 32 + quad * 8];
                acc[j] = __builtin_amdgcn_mfma_f32_16x16x32_bf16(af, bfr, acc[j], 0, 0, 0);
            }
        }
        __syncthreads();
    }

    float vv[4][4];
    #pragma unroll
    for (int j = 0; j < 4; ++j) {
        int col = wave * 64 + j * 16 + lm;
        float bj = bias[col];
        #pragma unroll
        for (int r = 0; r < 4; ++r) {
            int row = m0 + quad * 4 + r;
            vv[j][r] = acc[j][r] + bj + R[(size_t)row * D_MODEL + col];
        }
    }
    #pragma unroll
    for (int r = 0; r < 4; ++r) {
        float p = vv[0][r] * vv[0][r] + vv[1][r] * vv[1][r]
                + vv[2][r] * vv[2][r] + vv[3][r] * vv[3][r];
        p = row_allreduce16(p);
        if (lm == 0) sm.wout.rsum[quad * 4 + r][wave] = p;
    }
    __syncthreads();
    float rs[4];
    #pragma unroll
    for (int r = 0; r < 4; ++r) {
        int lr = quad * 4 + r;
        float tot = sm.wout.rsum[lr][0] + sm.wout.rsum[lr][1]
                  + sm.wout.rsum[lr][2] + sm.wout.rsum[lr][3];
        rs[r] = rsqrtf(tot * (1.f / D_MODEL) + 1e-5f);
    }
    #pragma unroll
    for (int j = 0; j < 4; ++j) {
        int col = wave * 64 + j * 16 + lm;
        float wj = nw[col];
        #pragma unroll
        for (int r = 0; r < 4; ++r) {
            int row = m0 + quad * 4 + r;
            C[(size_t)row * D_MODEL + col] = vv[j][r];
            Xn[(size_t)row * D_MODEL + col] = (bf16_t)(vv[j][r] * rs[r] * wj);
        }
    }
}

// ---------------------------------------------------------------------------
// The persistent mega-kernel: all 6 layers, 25 grid barriers, 1 dispatch.
// ---------------------------------------------------------------------------
__global__ __launch_bounds__(256, 2) void mamba_mega(
    const float* __restrict__ x_in,  const float* __restrict__ norm_w,
    const float* __restrict__ W_in,  const float* __restrict__ b_in,
    const float* __restrict__ conv_w, const float* __restrict__ W_x,
    const float* __restrict__ dt_w,  const float* __restrict__ dt_b,
    const float* __restrict__ A_log, const float* __restrict__ Dv,
    const float* __restrict__ W_out, const float* __restrict__ b_out,
    float* __restrict__ out,
    float* __restrict__ xz, float* __restrict__ uT, float* __restrict__ szT,
    float* __restrict__ xdbcT, float* __restrict__ deltaT,
    bf16_t* __restrict__ xn_bf, bf16_t* __restrict__ y_bf,
    bf16_t* __restrict__ Wi_bf, int* bar)
{
    __shared__ SMem sm;
    const int blk = blockIdx.x;
    const int tid = threadIdx.x;

    // ---- phase 0: weight casts (grid-stride) + layer-0 rmsnorm ----
    {
        const int n0 = N_LAYERS * 2 * D_INNER * D_MODEL / 4;
        const int n1 = N_LAYERS * 48 * D_INNER / 4;
        const int n2 = N_LAYERS * D_MODEL * D_INNER / 4;
        const int ntot = n0 + n1 + n2;
        for (int i = blk * 256 + tid; i < ntot; i += NBLK * 256) {
            const float* s; int off;
            if (i < n0)           { s = W_in;  off = i; }
            else if (i < n0 + n1) { s = W_x;   off = i - n0; }
            else                  { s = W_out; off = i - n0 - n1; }
            const float4 v = *(const float4*)(s + (size_t)off * 4);
            bf16x4 o;
            o[0] = (bf16_t)v.x; o[1] = (bf16_t)v.y;
            o[2] = (bf16_t)v.z; o[3] = (bf16_t)v.w;
            *(bf16x4*)(Wi_bf + (size_t)i * 4) = o;
        }
        // layer-0 rmsnorm: one row per wave (512 blocks x 4 waves = 2048 rows)
        {
            const int row  = blk * 4 + (tid >> 6);
            const int lane = tid & 63;
            const float4 v = *(const float4*)(x_in + (size_t)row * D_MODEL + lane * 4);
            float ss = v.x * v.x + v.y * v.y + v.z * v.z + v.w * v.w;
            #pragma unroll
            for (int off = 32; off; off >>= 1) ss += __shfl_xor(ss, off);
            float rsq = rsqrtf(ss * (1.f / D_MODEL) + 1e-5f);
            const float4 wv = *(const float4*)(norm_w + lane * 4);
            bf16x4 ov;
            ov[0] = (bf16_t)(v.x * rsq * wv.x);
            ov[1] = (bf16_t)(v.y * rsq * wv.y);
            ov[2] = (bf16_t)(v.z * rsq * wv.z);
            ov[3] = (bf16_t)(v.w * rsq * wv.w);
            *(bf16x4*)(xn_bf + (size_t)row * D_MODEL + lane * 4) = ov;
        }
    }
    gbar(bar);

    const bf16_t* Wx_bf = Wi_bf + (size_t)N_LAYERS * 2 * D_INNER * D_MODEL;
    const bf16_t* Wo_bf = Wx_bf + (size_t)N_LAYERS * 48 * D_INNER;

    for (int layer = 0; layer < N_LAYERS; ++layer) {
        // P1: win GEMM (all 512 blocks)
        phase_win(sm, xn_bf,
                  Wi_bf + (size_t)layer * 2 * D_INNER * D_MODEL,
                  b_in + (size_t)layer * 2 * D_INNER, xz, szT, blk);
        gbar(bar);

        // P2: conv + W_x + delta (blocks 0-127)
        if (blk < 128)
            phase_conv(sm, xz, conv_w + (size_t)layer * D_INNER * 4,
                       Wx_bf + (size_t)layer * 48 * D_INNER,
                       dt_w + (size_t)layer * D_INNER * DT_RANK,
                       dt_b + (size_t)layer * D_INNER,
                       uT, xdbcT, deltaT, blk);
        gbar(bar);

        // P3: scan (all 512 blocks)
        phase_scan(sm, xdbcT, deltaT, uT, szT,
                   A_log + (size_t)layer * D_INNER * D_STATE,
                   Dv + (size_t)layer * D_INNER, y_bf, blk);
        gbar(bar);

        // P4: wout + residual + next-layer norm (blocks 0-127)
        if (blk < 128) {
            const float* R = (layer == 0) ? x_in : out;
            phase_wout(sm, y_bf, Wo_bf + (size_t)layer * D_MODEL * D_INNER,
                       b_out + (size_t)layer * D_MODEL, R,
                       norm_w + (size_t)((layer + 1) % N_LAYERS) * D_MODEL,
                       out, xn_bf, blk);
        }
        gbar(bar);
    }
}

// ---------------------------------------------------------------------------
extern "C" void kernel_launch(void* const* d_in, const int* in_sizes, int n_in,
                              void* d_out, int out_size, void* d_ws, size_t ws_size,
                              hipStream_t stream)
{
    const float* x_in   = (const float*)d_in[0];
    const float* norm_w = (const float*)d_in[1];
    const float* W_in   = (const float*)d_in[2];
    const float* b_in   = (const float*)d_in[3];
    const float* conv_w = (const float*)d_in[4];
    const float* W_x    = (const float*)d_in[5];
    const float* dt_w   = (const float*)d_in[6];
    const float* dt_b   = (const float*)d_in[7];
    const float* A_log  = (const float*)d_in[8];
    const float* Dv     = (const float*)d_in[9];
    const float* W_out  = (const float*)d_in[10];
    const float* b_out  = (const float*)d_in[11];
    float* out = (float*)d_out;

    // fp32 scratch
    float* ws     = (float*)d_ws;
    float* xz     = ws;                        // 2048*512 (x half only)
    float* uT     = xz     + BL * D_INNER;     // 512*2048
    float* szT    = uT     + D_INNER * BL;     // 512*2048
    float* xdbcT  = szT    + D_INNER * BL;     // 48*2048
    float* deltaT = xdbcT  + 48 * BL;          // 512*2048
    // bf16 scratch
    bf16_t* bws   = (bf16_t*)(deltaT + D_INNER * BL);
    bf16_t* xn_bf = bws;                       // 2048*256
    bf16_t* y_bf  = xn_bf + BL * D_MODEL;      // 2048*512
    bf16_t* Wi_bf = y_bf  + BL * D_INNER;      // 6*1024*256 | Wx | Wo contiguous
    bf16_t* Wend  = Wi_bf + (size_t)N_LAYERS * 2 * D_INNER * D_MODEL
                          + (size_t)N_LAYERS * 48 * D_INNER
                          + (size_t)N_LAYERS * D_MODEL * D_INNER;
    int* bar = (int*)Wend;                     // 2 ints: (counter, generation)

    hipMemsetAsync(bar, 0, 2 * sizeof(int), stream);

    mamba_mega<<<NBLK, 256, 0, stream>>>(
        x_in, norm_w, W_in, b_in, conv_w, W_x, dt_w, dt_b, A_log, Dv,
        W_out, b_out, out,
        xz, uT, szT, xdbcT, deltaT,
        xn_bf, y_bf, Wi_bf, bar);
}

// Round 7
// 545.847 us; speedup vs baseline: 7.8417x; 7.8417x over previous
//
#include <hip/hip_runtime.h>
#include <hip/hip_bf16.h>

#define B_SZ 4
#define L_SZ 512
#define D_MODEL 256
#define D_INNER 512
#define D_STATE 16
#define DT_RANK 16
#define N_LAYERS 6
#define BL (B_SZ * L_SZ)   // 2048 token rows

typedef __bf16 bf16_t;
typedef __bf16 bf16x8 __attribute__((ext_vector_type(8)));
typedef __bf16 bf16x4 __attribute__((ext_vector_type(4)));
typedef float  f32x4  __attribute__((ext_vector_type(4)));

// All-reduce over the 16-lane DPP row via rotate-add.
__device__ __forceinline__ float row_allreduce16(float x)
{
    int v;
    v = __builtin_amdgcn_mov_dpp(__float_as_int(x), 0x121, 0xf, 0xf, true);
    x += __int_as_float(v);
    v = __builtin_amdgcn_mov_dpp(__float_as_int(x), 0x122, 0xf, 0xf, true);
    x += __int_as_float(v);
    v = __builtin_amdgcn_mov_dpp(__float_as_int(x), 0x124, 0xf, 0xf, true);
    x += __int_as_float(v);
    v = __builtin_amdgcn_mov_dpp(__float_as_int(x), 0x128, 0xf, 0xf, true);
    x += __int_as_float(v);
    return x;
}

// ---------------------------------------------------------------------------
// fp32 -> bf16 cast of the three weight tensors in one dispatch.
// ---------------------------------------------------------------------------
__global__ __launch_bounds__(256) void cast3_kernel(
    const float* __restrict__ s0, const float* __restrict__ s1,
    const float* __restrict__ s2, bf16_t* __restrict__ dst,
    int n0, int n1, int n2)
{
    int i = blockIdx.x * 256 + threadIdx.x;
    const float* s; int off;
    if (i < n0)            { s = s0; off = i; }
    else if (i < n0 + n1)  { s = s1; off = i - n0; }
    else if (i < n0+n1+n2) { s = s2; off = i - n0 - n1; }
    else return;
    const float4 v = *(const float4*)(s + (size_t)off * 4);
    bf16x4 o;
    o[0] = (bf16_t)v.x; o[1] = (bf16_t)v.y;
    o[2] = (bf16_t)v.z; o[3] = (bf16_t)v.w;
    *(bf16x4*)(dst + (size_t)i * 4) = o;
}

// ---------------------------------------------------------------------------
// RMSNorm -> bf16 output. Layer 0 only (others fused into gemm_wout_norm).
// ---------------------------------------------------------------------------
__global__ __launch_bounds__(256) void rmsnorm_kernel(
    const float* __restrict__ x, const float* __restrict__ w,
    bf16_t* __restrict__ o)
{
    int row  = blockIdx.x * 4 + (threadIdx.x >> 6);
    int lane = threadIdx.x & 63;
    const float4 v = *(const float4*)(x + (size_t)row * D_MODEL + lane * 4);
    float ss = v.x * v.x + v.y * v.y + v.z * v.z + v.w * v.w;
    #pragma unroll
    for (int off = 32; off; off >>= 1) ss += __shfl_xor(ss, off);
    float rs = rsqrtf(ss * (1.f / D_MODEL) + 1e-5f);
    const float4 wv = *(const float4*)(w + lane * 4);
    bf16x4 ov;
    ov[0] = (bf16_t)(v.x * rs * wv.x);
    ov[1] = (bf16_t)(v.y * rs * wv.y);
    ov[2] = (bf16_t)(v.z * rs * wv.z);
    ov[3] = (bf16_t)(v.w * rs * wv.w);
    *(bf16x4*)(o + (size_t)row * D_MODEL + lane * 4) = ov;
}

// ---------------------------------------------------------------------------
// W_in GEMM (K=256), full-K A staging + ZSPLIT epilogue.
// R22: xz and szT outputs now bf16 (halve the producer->consumer stream).
// ---------------------------------------------------------------------------
__global__ __launch_bounds__(256) void win_kernel(
    const bf16_t* __restrict__ A,      // xn_bf (BL, 256)
    const bf16_t* __restrict__ Bw,     // Wi_bf (1024, 256)
    const float* __restrict__ bias,    // (1024)
    bf16_t* __restrict__ C,            // xz x-half (BL, 512) bf16
    bf16_t* __restrict__ Z)            // szT (512, BL) bf16
{
    constexpr int K = 256, BK = 64;
    __shared__ bf16_t As[64][K + 8];   // full-K A
    __shared__ bf16_t Bs[64][BK + 8];

    const int tid  = threadIdx.x;
    const int wave = tid >> 6, lane = tid & 63;
    const int wm = wave >> 1, wn = wave & 1;
    const int lm = lane & 15, quad = lane >> 4;
    const int m0 = blockIdx.y * 64, n0 = blockIdx.x * 64;

    #pragma unroll
    for (int i = tid; i < 64 * (K / 8); i += 256) {
        int r = i >> 5, c8 = i & 31;
        *(bf16x8*)&As[r][c8 * 8] =
            *(const bf16x8*)(A + (size_t)(m0 + r) * K + c8 * 8);
    }

    f32x4 acc[2][2] = {};
    for (int k0 = 0; k0 < K; k0 += BK) {
        #pragma unroll
        for (int i = tid; i < 64 * (BK / 8); i += 256) {
            int r = i >> 3, c8 = i & 7;
            *(bf16x8*)&Bs[r][c8 * 8] =
                *(const bf16x8*)(Bw + (size_t)(n0 + r) * K + k0 + c8 * 8);
        }
        __syncthreads();   // first barrier also covers the As staging
        #pragma unroll
        for (int ks = 0; ks < 2; ++ks) {
            bf16x8 af[2], bfr[2];
            #pragma unroll
            for (int i = 0; i < 2; ++i)
                af[i] = *(const bf16x8*)&As[wm * 32 + i * 16 + lm][k0 + ks * 32 + quad * 8];
            #pragma unroll
            for (int j = 0; j < 2; ++j)
                bfr[j] = *(const bf16x8*)&Bs[wn * 32 + j * 16 + lm][ks * 32 + quad * 8];
            #pragma unroll
            for (int i = 0; i < 2; ++i)
                #pragma unroll
                for (int j = 0; j < 2; ++j)
                    acc[i][j] = __builtin_amdgcn_mfma_f32_16x16x32_bf16(
                        af[i], bfr[j], acc[i][j], 0, 0, 0);
        }
        __syncthreads();
    }

    if (n0 >= D_INNER) {
        // z half: bias + silu, transposed bf16x4 stores into Z (d-major)
        #pragma unroll
        for (int i = 0; i < 2; ++i) {
            int rowbase = m0 + wm * 32 + i * 16 + quad * 4;
            #pragma unroll
            for (int j = 0; j < 2; ++j) {
                int col = n0 + wn * 32 + j * 16 + lm;
                bf16x4 o;
                #pragma unroll
                for (int r = 0; r < 4; ++r) {
                    float v = acc[i][j][r] + bias[col];
                    o[r] = (bf16_t)(v / (1.f + __expf(-v)));
                }
                *(bf16x4*)(Z + (size_t)(col - D_INNER) * BL + rowbase) = o;
            }
        }
        return;
    }

    #pragma unroll
    for (int i = 0; i < 2; ++i) {
        #pragma unroll
        for (int j = 0; j < 2; ++j) {
            int col = n0 + wn * 32 + j * 16 + lm;
            #pragma unroll
            for (int r = 0; r < 4; ++r) {
                int rowm = m0 + wm * 32 + i * 16 + quad * 4 + r;
                C[(size_t)rowm * D_INNER + col] = (bf16_t)(acc[i][j][r] + bias[col]);
            }
        }
    }
}

// ---------------------------------------------------------------------------
// W_out GEMM + residual + fused next-layer RMSNorm (R21, unchanged).
// ---------------------------------------------------------------------------
__global__ __launch_bounds__(256) void gemm_wout_norm(
    const bf16_t* __restrict__ A,      // y_bf (BL, 512)
    const bf16_t* __restrict__ Bw,     // Wo_bf (256, 512)
    const float* __restrict__ bias,    // (256)
    const float* __restrict__ R,       // residual xcur (BL, 256)
    const float* __restrict__ nw,      // norm_w of NEXT layer (256)
    float* __restrict__ C,             // out (BL, 256)
    bf16_t* __restrict__ Xn)           // xn_bf (BL, 256) for next layer
{
    constexpr int K = 512, BK = 64, BM = 16, BN = 256, LDK = BK + 8;
    __shared__ bf16_t As[BM][LDK];
    __shared__ bf16_t Bs[BN][LDK];
    __shared__ float rsum[BM][5];

    const int tid  = threadIdx.x;
    const int wave = tid >> 6, lane = tid & 63;
    const int lm = lane & 15, quad = lane >> 4;
    const int m0 = blockIdx.x * BM;

    f32x4 acc[4] = {};
    for (int k0 = 0; k0 < K; k0 += BK) {
        if (tid < BM * (BK / 8)) {
            int r = tid >> 3, c8 = tid & 7;
            *(bf16x8*)&As[r][c8 * 8] =
                *(const bf16x8*)(A + (size_t)(m0 + r) * K + k0 + c8 * 8);
        }
        #pragma unroll
        for (int i = tid; i < BN * (BK / 8); i += 256) {
            int r = i >> 3, c8 = i & 7;
            *(bf16x8*)&Bs[r][c8 * 8] =
                *(const bf16x8*)(Bw + (size_t)r * K + k0 + c8 * 8);
        }
        __syncthreads();
        #pragma unroll
        for (int ks = 0; ks < 2; ++ks) {
            bf16x8 af = *(const bf16x8*)&As[lm][ks * 32 + quad * 8];
            #pragma unroll
            for (int j = 0; j < 4; ++j) {
                bf16x8 bfr = *(const bf16x8*)&Bs[wave * 64 + j * 16 + lm][ks * 32 + quad * 8];
                acc[j] = __builtin_amdgcn_mfma_f32_16x16x32_bf16(af, bfr, acc[j], 0, 0, 0);
            }
        }
        __syncthreads();
    }

    float vv[4][4];
    #pragma unroll
    for (int j = 0; j < 4; ++j) {
        int col = wave * 64 + j * 16 + lm;
        float bj = bias[col];
        #pragma unroll
        for (int r = 0; r < 4; ++r) {
            int row = m0 + quad * 4 + r;
            vv[j][r] = acc[j][r] + bj + R[(size_t)row * D_MODEL + col];
        }
    }
    #pragma unroll
    for (int r = 0; r < 4; ++r) {
        float p = vv[0][r] * vv[0][r] + vv[1][r] * vv[1][r]
                + vv[2][r] * vv[2][r] + vv[3][r] * vv[3][r];
        p = row_allreduce16(p);
        if (lm == 0) rsum[quad * 4 + r][wave] = p;
    }
    __syncthreads();
    float rs[4];
    #pragma unroll
    for (int r = 0; r < 4; ++r) {
        int lr = quad * 4 + r;
        float tot = rsum[lr][0] + rsum[lr][1] + rsum[lr][2] + rsum[lr][3];
        rs[r] = rsqrtf(tot * (1.f / D_MODEL) + 1e-5f);
    }
    #pragma unroll
    for (int j = 0; j < 4; ++j) {
        int col = wave * 64 + j * 16 + lm;
        float wj = nw[col];
        #pragma unroll
        for (int r = 0; r < 4; ++r) {
            int row = m0 + quad * 4 + r;
            C[(size_t)row * D_MODEL + col] = vv[j][r];
            Xn[(size_t)row * D_MODEL + col] = (bf16_t)(vv[j][r] * rs[r] * wj);
        }
    }
}

// ---------------------------------------------------------------------------
// Fused conv+silu + W_x GEMM + delta precompute.
// R22: xz input bf16 (converted to fp32 in LDS), uT output bf16.
// ---------------------------------------------------------------------------
__global__ __launch_bounds__(256) void wx_conv_kernel(
    const bf16_t* __restrict__ xzx,   // (BL, 512) x half, m-major, bf16
    const float* __restrict__ cw,     // (512, 4)
    const bf16_t* __restrict__ Bw,    // Wx_bf (48, 512)
    const float* __restrict__ dt_w,   // (512, 16)
    const float* __restrict__ dt_b,   // (512)
    bf16_t* __restrict__ uT,          // (512, BL) bf16
    float* __restrict__ xdbcT,        // (48, BL)
    float* __restrict__ deltaT)       // (512, BL) fp32 (exp-sensitive)
{
    constexpr int K = 512;
    __shared__ float  xs[19][516];    // xz rows m0-3..m0+15 (fp32 in LDS)
    __shared__ bf16_t us[16][520];    // u tile, [m][k], bf16
    __shared__ f32x4  part[4][3][64];
    __shared__ float  dtt[16][17];    // dt tile, [t][k]

    const int tid  = threadIdx.x;
    const int wave = tid >> 6, lane = tid & 63;
    const int lm = lane & 15, quad = lane >> 4;
    const int m0 = blockIdx.x * 16;

    // stage xs: 19 rows x 64 chunks of 8 bf16 -> fp32 LDS
    for (int q = tid; q < 19 * 64; q += 256) {
        int rx = q >> 6, c8 = (q & 63) * 8;
        int mr = m0 - 3 + rx;
        if (mr >= 0) {
            bf16x8 v = *(const bf16x8*)(xzx + (size_t)mr * K + c8);
            #pragma unroll
            for (int e = 0; e < 8; ++e) xs[rx][c8 + e] = (float)v[e];
        } else {
            #pragma unroll
            for (int e = 0; e < 8; ++e) xs[rx][c8 + e] = 0.f;
        }
    }
    __syncthreads();

    #pragma unroll
    for (int it = 0; it < 8; ++it) {
        int item = tid + it * 256;
        int d = item >> 2, rg = item & 3;
        const float4 wv = *(const float4*)(cw + d * 4);
        bf16x4 ob;
        #pragma unroll
        for (int e = 0; e < 4; ++e) {
            int ro = rg * 4 + e;
            int t  = (m0 + ro) & (L_SZ - 1);
            float a = wv.w * xs[ro + 3][d];
            if (t >= 1) a += wv.z * xs[ro + 2][d];
            if (t >= 2) a += wv.y * xs[ro + 1][d];
            if (t >= 3) a += wv.x * xs[ro + 0][d];
            a = a / (1.f + __expf(-a));
            ob[e] = (bf16_t)a;
            us[ro][d] = (bf16_t)a;
        }
        *(bf16x4*)(uT + (size_t)d * BL + m0 + rg * 4) = ob;
    }
    __syncthreads();

    f32x4 acc[3] = {};
    const int kb = wave * 128 + quad * 8;
    #pragma unroll
    for (int ks = 0; ks < 4; ++ks) {
        int k0 = kb + ks * 32;
        bf16x8 af = *(const bf16x8*)&us[lm][k0];
        #pragma unroll
        for (int j = 0; j < 3; ++j) {
            bf16x8 bfr = *(const bf16x8*)(Bw + (size_t)(j * 16 + lm) * K + k0);
            acc[j] = __builtin_amdgcn_mfma_f32_16x16x32_bf16(af, bfr, acc[j], 0, 0, 0);
        }
    }
    #pragma unroll
    for (int j = 0; j < 3; ++j) part[wave][j][lane] = acc[j];
    __syncthreads();

    if (tid < 192) {
        int j = tid >> 6, l = tid & 63;
        f32x4 s = part[0][j][l];
        s += part[1][j][l];
        s += part[2][j][l];
        s += part[3][j][l];
        int col = j * 16 + (l & 15);
        float4 v = make_float4(s[0], s[1], s[2], s[3]);
        *(float4*)(xdbcT + (size_t)col * BL + m0 + (l >> 4) * 4) = v;
        if (j == 0) {
            #pragma unroll
            for (int e = 0; e < 4; ++e)
                dtt[(l >> 4) * 4 + e][l & 15] = s[e];
        }
    }
    __syncthreads();

    // ---- delta = softplus(dt @ dt_w^T + dt_b) for 512 d x 16 tokens ----
    #pragma unroll
    for (int it = 0; it < 8; ++it) {
        int item = tid + it * 256;
        int d = item >> 2, tg = item & 3;
        const float4 w0 = *(const float4*)(dt_w + (size_t)d * 16 + 0);
        const float4 w1 = *(const float4*)(dt_w + (size_t)d * 16 + 4);
        const float4 w2 = *(const float4*)(dt_w + (size_t)d * 16 + 8);
        const float4 w3 = *(const float4*)(dt_w + (size_t)d * 16 + 12);
        const float bdt = dt_b[d];
        float4 o;
        #pragma unroll
        for (int e = 0; e < 4; ++e) {
            int t = tg * 4 + e;
            float a = bdt;
            a += dtt[t][0]  * w0.x + dtt[t][1]  * w0.y + dtt[t][2]  * w0.z + dtt[t][3]  * w0.w;
            a += dtt[t][4]  * w1.x + dtt[t][5]  * w1.y + dtt[t][6]  * w1.z + dtt[t][7]  * w1.w;
            a += dtt[t][8]  * w2.x + dtt[t][9]  * w2.y + dtt[t][10] * w2.z + dtt[t][11] * w2.w;
            a += dtt[t][12] * w3.x + dtt[t][13] * w3.y + dtt[t][14] * w3.z + dtt[t][15] * w3.w;
            ((float*)&o)[e] = (a > 20.f) ? a : __logf(1.f + __expf(a));
        }
        *(float4*)(deltaT + (size_t)d * BL + m0 + tg * 4) = o;
    }
}

// ---------------------------------------------------------------------------
// Selective scan v9 + R22: uT/szT inputs bf16 (math stays fp32).
// ---------------------------------------------------------------------------
__global__ __launch_bounds__(1024, 4) void scan_kernel(
    const float* __restrict__ xdbcT,  // (48, BL): [dt | B | C]
    const float* __restrict__ deltaT, // (512, BL) fp32
    const bf16_t* __restrict__ uT,    // (512, BL) bf16
    const bf16_t* __restrict__ szT,   // (512, BL) bf16
    const float* __restrict__ A_log,  // (512, 16)
    const float* __restrict__ Dv,     // (512)
    bf16_t* __restrict__ y)           // (BL, 512) bf16
{
    constexpr int TC = 32;
    constexpr int NW = L_SZ / TC;     // 16 waves

    int blk  = blockIdx.x;            // 512 blocks: b*128 + dg
    int b    = blk >> 7;
    int dg   = blk & 127;
    int wave = threadIdx.x >> 6;
    int lane = threadIdx.x & 63;
    int d    = dg * 4 + (lane >> 4);
    int n    = lane & 15;

    __shared__ float lds_Ap[NW][64];
    __shared__ float lds_he[NW][64];

    float Adn = -__expf(A_log[d * D_STATE + n]);
    int r0 = b * L_SZ + wave * TC;

    const float* Brow  = xdbcT  + (size_t)(DT_RANK + n) * BL;
    const float* Crow  = xdbcT  + (size_t)(DT_RANK + D_STATE + n) * BL;
    const float* drow  = deltaT + (size_t)d * BL;
    const bf16_t* urow = uT     + (size_t)d * BL;
    const bf16_t* zrow = szT    + (size_t)d * BL;

    // ---- pass 1: chunk-end state only (running h and P = prod dA) ----
    {
        float h = 0.f, P = 1.f;
        #pragma unroll
        for (int j4 = 0; j4 < 8; ++j4) {
            int rb = r0 + j4 * 4;
            f32x4 dl = *(const f32x4*)(drow + rb);
            f32x4 Bv = *(const f32x4*)(Brow + rb);
            bf16x4 ub = *(const bf16x4*)(urow + rb);
            #pragma unroll
            for (int k = 0; k < 4; ++k) {
                float dA = __expf(dl[k] * Adn);
                h = dA * h + dl[k] * (float)ub[k] * Bv[k];
                P *= dA;
            }
        }
        lds_Ap[wave][lane] = P;
        lds_he[wave][lane] = h;
    }
    __syncthreads();

    // ---- cross-wave carry: H = state entering this wave's chunk ----
    float H = 0.f;
    for (int j = 0; j < wave; ++j)
        H = lds_Ap[j][lane] * H + lds_he[j][lane];

    // ---- pass 2: re-run recurrence seeded with H; emit y ----
    float Dd = Dv[d];
    float h = H;
    #pragma unroll
    for (int g = 0; g < 2; ++g) {
        float py[16];
        #pragma unroll
        for (int j4 = 0; j4 < 4; ++j4) {
            int rb = r0 + g * 16 + j4 * 4;
            f32x4 dl = *(const f32x4*)(drow + rb);
            f32x4 Bv = *(const f32x4*)(Brow + rb);
            bf16x4 ub = *(const bf16x4*)(urow + rb);
            f32x4 Cc = *(const f32x4*)(Crow + rb);
            #pragma unroll
            for (int k = 0; k < 4; ++k) {
                float dA = __expf(dl[k] * Adn);
                h = dA * h + dl[k] * (float)ub[k] * Bv[k];
                py[j4 * 4 + k] = h * Cc[k];
            }
        }
        #pragma unroll
        for (int j = 0; j < 16; ++j)
            py[j] = row_allreduce16(py[j]);
        if (n == 0) {
            #pragma unroll
            for (int j4 = 0; j4 < 4; ++j4) {
                int rb = r0 + g * 16 + j4 * 4;
                bf16x4 ub = *(const bf16x4*)(urow + rb);
                bf16x4 zb = *(const bf16x4*)(zrow + rb);
                #pragma unroll
                for (int k = 0; k < 4; ++k) {
                    int row = rb + k;
                    y[(size_t)row * D_INNER + d] =
                        (bf16_t)((py[j4*4+k] + (float)ub[k] * Dd) * (float)zb[k]);
                }
            }
        }
    }
}

// ---------------------------------------------------------------------------
extern "C" void kernel_launch(void* const* d_in, const int* in_sizes, int n_in,
                              void* d_out, int out_size, void* d_ws, size_t ws_size,
                              hipStream_t stream)
{
    const float* x_in   = (const float*)d_in[0];
    const float* norm_w = (const float*)d_in[1];
    const float* W_in   = (const float*)d_in[2];
    const float* b_in   = (const float*)d_in[3];
    const float* conv_w = (const float*)d_in[4];
    const float* W_x    = (const float*)d_in[5];
    const float* dt_w   = (const float*)d_in[6];
    const float* dt_b   = (const float*)d_in[7];
    const float* A_log  = (const float*)d_in[8];
    const float* Dv     = (const float*)d_in[9];
    const float* W_out  = (const float*)d_in[10];
    const float* b_out  = (const float*)d_in[11];
    float* out = (float*)d_out;

    // fp32 scratch
    float* ws     = (float*)d_ws;
    float* xdbcT  = ws;                        // 48*2048
    float* deltaT = xdbcT + 48 * BL;           // 512*2048
    // bf16 scratch
    bf16_t* bws   = (bf16_t*)(deltaT + D_INNER * BL);
    bf16_t* xz    = bws;                       // 2048*512 (x half, bf16)
    bf16_t* uT    = xz    + BL * D_INNER;      // 512*2048
    bf16_t* szT   = uT    + D_INNER * BL;      // 512*2048
    bf16_t* xn_bf = szT   + D_INNER * BL;      // 2048*256
    bf16_t* y_bf  = xn_bf + BL * D_MODEL;      // 2048*512
    bf16_t* Wi_bf = y_bf  + BL * D_INNER;      // 6*1024*256
    bf16_t* Wx_bf = Wi_bf + N_LAYERS * 2 * D_INNER * D_MODEL;
    bf16_t* Wo_bf = Wx_bf + N_LAYERS * 48 * D_INNER;

    // ---- weight casts, one dispatch (dsts contiguous: Wi|Wx|Wo) ----
    {
        int n0 = N_LAYERS * 2 * D_INNER * D_MODEL / 4;
        int n1 = N_LAYERS * 48 * D_INNER / 4;
        int n2 = N_LAYERS * D_MODEL * D_INNER / 4;
        cast3_kernel<<<(n0 + n1 + n2 + 255) / 256, 256, 0, stream>>>(
            W_in, W_x, W_out, Wi_bf, n0, n1, n2);
    }

    // layer 0's norm (reads x_in); later norms fused into gemm_wout_norm
    rmsnorm_kernel<<<BL / 4, 256, 0, stream>>>(x_in, norm_w, xn_bf);

    for (int i = 0; i < N_LAYERS; ++i) {
        const float* xcur = (i == 0) ? x_in : out;

        // xz(x half, bf16) + szT(z half, silu, transposed, bf16)
        win_kernel<<<dim3(1024 / 64, 2048 / 64), 256, 0, stream>>>(
            xn_bf, Wi_bf + (size_t)i * 2 * D_INNER * D_MODEL,
            b_in + i * 2 * D_INNER, xz, szT);

        // conv+silu fused with W_x GEMM + delta precompute
        wx_conv_kernel<<<BL / 16, 256, 0, stream>>>(
            xz, conv_w + i * D_INNER * 4,
            Wx_bf + (size_t)i * 48 * D_INNER,
            dt_w + (size_t)i * D_INNER * DT_RANK, dt_b + i * D_INNER,
            uT, xdbcT, deltaT);

        // scan v9 (bf16 u/sz inputs)
        scan_kernel<<<512, 1024, 0, stream>>>(
            xdbcT, deltaT, uT, szT,
            A_log + (size_t)i * D_INNER * D_STATE, Dv + i * D_INNER, y_bf);

        // out = xcur + y @ W_out^T + b_out, fused with next layer's rmsnorm
        const float* nw_next = norm_w + (size_t)((i + 1) % N_LAYERS) * D_MODEL;
        gemm_wout_norm<<<BL / 16, 256, 0, stream>>>(
            y_bf, Wo_bf + (size_t)i * D_MODEL * D_INNER,
            b_out + i * D_MODEL, xcur, nw_next, out, xn_bf);
    }
}